// Round 2
// 183.688 us; speedup vs baseline: 1.0269x; 1.0269x over previous
//
#include <hip/hip_runtime.h>
#include <hip/hip_bf16.h>

// Problem constants
#define NB 256
#define NACT 21
#define NA 8192
#define NE 262144
#define CSR_CAP 128
#define LOG2E 1.44269504f

#if __has_builtin(__builtin_amdgcn_exp2f)
#define EXP2F(x) __builtin_amdgcn_exp2f(x)
#else
#define EXP2F(x) exp2f(x)
#endif

typedef __attribute__((ext_vector_type(8))) short short8;
typedef __attribute__((ext_vector_type(4))) float float4v;

__device__ inline float wsum64(float v) {
#pragma unroll
  for (int m = 32; m > 0; m >>= 1) v += __shfl_xor(v, m, 64);
  return v;
}

__device__ inline unsigned short f2bf(float f) {
  union { __hip_bfloat16 h; unsigned short u; } cv;
  cv.h = __float2bfloat16(f);
  return cv.u;
}

// ---------------- k_init: zero cnt (action passthrough lives in k_he) ----------------
__global__ __launch_bounds__(512) void k_init(int* cnt) {
  int i = blockIdx.x * 512 + threadIdx.x;  // 16*512 = 8192
  cnt[i] = 0;
}

// ---------------- k_pc: fused prep (blocks 0..511) + conv (blocks 512..767) ----------------
// prep: CSR build + fcw->bf16 + W2 transpose/partials.  conv: conv1+conv2 per image.
__global__ __launch_bounds__(512, 2) void k_pc(
    const int* __restrict__ edges, const float* __restrict__ fcw,
    const float* __restrict__ g2w, const float* __restrict__ g2b,
    unsigned short* fcwbf, unsigned short* w2t, float* wpart, int* cnt, int* csr,
    const float* __restrict__ x, const float* __restrict__ c1w, const float* __restrict__ c1b,
    const float* __restrict__ c2w, const float* __restrict__ c2b, unsigned short* h1024bf) {
  __shared__ float sm[8109];  // conv: xs[845] w1s[1440] c1s[1152] w2s[64*73]; prep: red[16][17] b2s[16]
  int t = threadIdx.x;
  if (blockIdx.x < 512) {  // ---- prep ----
    float (*red)[17] = (float(*)[17])sm;
    float* b2s = sm + 272;
    int blk = blockIdx.x;
    {  // CSR: 1 edge per thread (512*512 = NE)
      int e = blk * 512 + t;
      int s = edges[2 * e], d = edges[2 * e + 1];
      int slot = atomicAdd(&cnt[d], 1);
      if (slot < CSR_CAP) csr[d * CSR_CAP + slot] = s;
    }
    {  // fcw -> bf16: 2 floats per thread
      int base = (blk * 512 + t) * 2;
      float2 v = *(const float2*)&fcw[base];
      fcwbf[base + 0] = f2bf(v.x);
      fcwbf[base + 1] = f2bf(v.y);
    }
    {  // W2: block owns 16 cols; w2t[j][k] = W2[k][j] bf16; column partial sums
      if (t < 256) {
        int jj = t >> 4, k = t & 15;
        int j = blk * 16 + jj;
        float w = g2w[k * 8192 + j];
        w2t[j * 16 + k] = f2bf(w);
        red[jj][k] = w;
      }
      if (t < 16) b2s[t] = g2b[blk * 16 + t];
      __syncthreads();
      if (t < 16) {
        float s = 0.0f;
#pragma unroll
        for (int q = 0; q < 16; q++) s += red[q][t];
        wpart[blk * 17 + t] = s;
      } else if (t == 16) {
        float s = 0.0f;
#pragma unroll
        for (int q = 0; q < 16; q++) s += b2s[q];
        wpart[blk * 17 + 16] = s;
      }
    }
  } else {  // ---- conv ----
    float* xs = sm;
    float* w1s = sm + 845;
    float* c1s = sm + 2285;
    float* w2s = sm + 3437;  // 64*73
    int blk = blockIdx.x - 512;
    for (int i = t; i < 845; i += 512) xs[i] = x[blk * 845 + i];
    for (int i = t; i < 1440; i += 512) w1s[i] = c1w[i];
    __syncthreads();
    for (int idx = t; idx < 1152; idx += 512) {
      int oc = idx / 36, p = idx - oc * 36;
      int oy = p / 6, ox = p - oy * 6;
      float acc = c1b[oc];
      const float* wp = &w1s[oc * 45];
#pragma unroll
      for (int ic = 0; ic < 5; ic++)
#pragma unroll
        for (int ky = 0; ky < 3; ky++)
#pragma unroll
          for (int kx = 0; kx < 3; kx++)
            acc += xs[ic * 169 + (oy * 2 + ky) * 13 + ox * 2 + kx] * wp[ic * 9 + ky * 3 + kx];
      c1s[idx] = fmaxf(acc, 0.0f);
    }
    int p = t & 15, oc2 = t >> 4;  // 2 output channels per thread
    int oy = p >> 2, ox = p & 3;
    float a0 = c2b[oc2 * 2 + 0], a1 = c2b[oc2 * 2 + 1];
    for (int icb = 0; icb < 32; icb += 8) {
      __syncthreads();
      for (int i = t; i < 4608; i += 512) {
        int oc = i / 72, r = i - oc * 72;
        w2s[oc * 73 + r] = c2w[oc * 288 + icb * 9 + r];
      }
      __syncthreads();
#pragma unroll
      for (int ic = 0; ic < 8; ic++) {
#pragma unroll
        for (int ky = 0; ky < 3; ky++) {
#pragma unroll
          for (int kx = 0; kx < 3; kx++) {
            float cvv = c1s[(icb + ic) * 36 + (oy + ky) * 6 + ox + kx];
            int wi = ic * 9 + ky * 3 + kx;
            a0 += cvv * w2s[(oc2 * 2 + 0) * 73 + wi];
            a1 += cvv * w2s[(oc2 * 2 + 1) * 73 + wi];
          }
        }
      }
    }
    unsigned short* hp = &h1024bf[blk * 1024];
    hp[(oc2 * 2 + 0) * 16 + p] = f2bf(fmaxf(a0, 0.0f));
    hp[(oc2 * 2 + 1) * 16 + p] = f2bf(fmaxf(a1, 0.0f));
  }
}

// ---------------- k_fc: FC via bf16 MFMA (1 tile/block, K-split 4) + dinv/xs2 + wsf ----------------
__global__ __launch_bounds__(256, 4) void k_fc(
    const int* __restrict__ cnt, const float* __restrict__ x_msg,
    const unsigned short* __restrict__ h1024bf, const unsigned short* __restrict__ fcwbf,
    const float* __restrict__ fcb, const float* __restrict__ wpart,
    float* hidden, float* dinv, float* xs2, float* wsf) {
  __shared__ float red[4][256];
  int t = threadIdx.x, blk = blockIdx.x;
  if (blk == 512) {  // one extra block: reduce wpart -> wsf[17] (once, not per-msg-block)
    if (t < 17) {
      float s = 0.0f;
      for (int b = 0; b < 512; b++) s += wpart[b * 17 + t];
      wsf[t] = s;
    }
    return;
  }
  int wave = t >> 6, lane = t & 63;
  if (blk < 32) {
    int i = blk * 256 + t;
    float d = rsqrtf((float)cnt[i] + 1.0f);
    dinv[i] = d;
    xs2[i] = d * x_msg[i];
  }
  int tr = blk >> 5, tc = blk & 31;  // 16 row-tiles x 32 col-tiles
  int m = lane & 15, quad = lane >> 4;
  const unsigned short* ap = &h1024bf[(tr * 16 + m) * 1024 + wave * 256 + quad * 8];
  const unsigned short* bp = &fcwbf[(tc * 16 + m) * 1024 + wave * 256 + quad * 8];
  float4v acc = {0.0f, 0.0f, 0.0f, 0.0f};
#pragma unroll
  for (int i = 0; i < 8; i++) {
    short8 a = *(const short8*)(ap + i * 32);
    short8 b = *(const short8*)(bp + i * 32);
    acc = __builtin_amdgcn_mfma_f32_16x16x32_bf16(a, b, acc, 0, 0, 0);
  }
#pragma unroll
  for (int r = 0; r < 4; r++) red[wave][(quad * 4 + r) * 16 + m] = acc[r];
  __syncthreads();
  {  // reduce 4 K-slices + bias + relu
    float s = red[0][t] + red[1][t] + red[2][t] + red[3][t];
    int gr = tr * 16 + (t >> 4);
    int gc = tc * 16 + (t & 15);
    hidden[gr * 512 + gc] = fmaxf(s + fcb[gc], 0.0f);
  }
}

// ---------------- k_he: head (blocks 0..63) | enc (blocks 64..511) ----------------
__global__ __launch_bounds__(512, 2) void k_he(
    const float* __restrict__ hidden, const float* __restrict__ muw,
    const float* __restrict__ mub, const float* __restrict__ msgw,
    const float* __restrict__ msgb, const float* __restrict__ dinv,
    const int* __restrict__ action, float* es2, float* out) {
  __shared__ float muT[10752];
  __shared__ float hrows[2048];
  int t = threadIdx.x, blk = blockIdx.x;
  int wave = t >> 6, lane = t & 63;
  if (blk < 64) {  // head: 4 batch rows per block
    int b0 = blk * 4;
    for (int i = t; i < 10752; i += 512) {
      int a = i >> 9, k = i & 511;
      muT[k * 21 + a] = muw[i];
    }
    for (int i = t; i < 2048; i += 512) hrows[i] = hidden[b0 * 512 + i];
    __syncthreads();
    if (wave < 4) {
      int b = b0 + wave;
      float logit = -1e30f;
      if (lane < NACT) {
        float acc = mub[lane];
        const float* hr = &hrows[wave * 512];
        for (int k = 0; k < 512; k++) acc += hr[k] * muT[k * 21 + lane];
        logit = acc;
      }
      float m = logit;
#pragma unroll
      for (int s = 32; s > 0; s >>= 1) m = fmaxf(m, __shfl_xor(m, s, 64));
      float e = (lane < NACT) ? __expf(logit - m) : 0.0f;
      float se = wsum64(e);
      float swl = wsum64(e * logit);
      float lse = m + __logf(se);
      int act = action[b];
      if (lane == 0) {
        out[b] = (float)act;                  // action passthrough (was k_init)
        out[8704 + b] = lse - swl / se;       // entropy
      }
      if (lane == act) out[8448 + b] = logit - lse;  // log_prob
    }
  } else {  // enc: es2[j] = dinv[j] * (hidden[0].msg_w[j] + msgb[j])
    int wg = (blk - 64) * 8 + wave;  // 0..3583
    for (int j = wg; j < NA; j += 3584) {
      const float* wp = &msgw[j * 512 + lane * 8];
      float4 w0 = *(const float4*)(wp);
      float4 w1 = *(const float4*)(wp + 4);
      float4 h0 = *(const float4*)&hidden[lane * 8];
      float4 h1 = *(const float4*)&hidden[lane * 8 + 4];
      float s = w0.x * h0.x + w0.y * h0.y + w0.z * h0.z + w0.w * h0.w +
                w1.x * h1.x + w1.y * h1.y + w1.z * h1.z + w1.w * h1.w;
      s = wsum64(s);
      if (lane == 0) es2[j] = dinv[j] * (s + msgb[j]);
    }
  }
}

// ---------------- k_g1: GCN1 gather (2 rows per wave, 512 blocks) ----------------
__global__ __launch_bounds__(512, 4) void k_g1(
    const int* __restrict__ cnt, const int* __restrict__ csr,
    const float* __restrict__ dinv, const float* __restrict__ xs2,
    const float* __restrict__ es2, const float* __restrict__ g1w,
    const float* __restrict__ g1b, float* gbuf2) {
  int t = threadIdx.x, blk = blockIdx.x;
  int wave = t >> 6, lane = t & 63;
  int wg = blk * 8 + wave;  // 0..4095
#pragma unroll
  for (int rr = 0; rr < 2; rr++) {
    int i = wg * 2 + rr;
    int ci = min(cnt[i], CSR_CAP);
    float di = dinv[i];
    float a0 = 0.0f, a1 = 0.0f;
    for (int e = lane; e < ci; e += 64) {
      int s = csr[i * CSR_CAP + e];
      a0 += xs2[s];
      a1 += es2[s];
    }
    // self-loop coeff di^2: di*(sum_s dinv[s]x[s] + dinv[i]x[i])
    float f0 = (wsum64(a0) + xs2[i]) * di;
    float f1 = (wsum64(a1) + es2[i]) * di;
    if (lane < 16) {
      float gv = fmaxf(f0 * g1w[lane] + f1 * g1w[16 + lane] + g1b[lane], 0.0f);
      gbuf2[i * 16 + lane] = di * gv;
    }
  }
}

// ---------------- k_msg: GCN2 gather + MFMA scores + sum-exp (16 rows/block, 512 blocks) ----------------
__global__ __launch_bounds__(512, 2) void k_msg(
    const int* __restrict__ cnt, const int* __restrict__ csr,
    const float* __restrict__ dinv, const float* __restrict__ gbuf2,
    const float* __restrict__ wsf, const unsigned short* __restrict__ w2t,
    const float* __restrict__ g2b, float* out) {
  __shared__ __align__(16) unsigned short vbf[256];
  __shared__ float vf[256];
  __shared__ float pl[2048];
  __shared__ float sl[128];
  __shared__ float wsfs[17];
  int t = threadIdx.x, blk = blockIdx.x;
  int wave = t >> 6, lane = t & 63;
  int rowbase = blk * 16;
  if (t < 17) wsfs[t] = wsf[t];
  {  // gather 16 V rows: 8 waves x 2 rows; lanes = 4 edge-groups x 16 cols
    int eq = lane >> 4, c = lane & 15;
#pragma unroll
    for (int rr = 0; rr < 2; rr++) {
      int il = wave * 2 + rr;
      int i = rowbase + il;
      int ci = min(cnt[i], CSR_CAP);
      float di = dinv[i];
      float acc = (eq == 0) ? gbuf2[i * 16 + c] : 0.0f;  // self: di*(...+gbuf2[i]) = di^2*g_i
      for (int e = eq; e < ci; e += 4) {
        int s = csr[i * CSR_CAP + e];
        acc += gbuf2[s * 16 + c];
      }
      acc *= di;
      acc += __shfl_xor(acc, 16, 64);
      acc += __shfl_xor(acc, 32, 64);
      if (eq == 0) {
        vf[il * 16 + c] = acc;
        vbf[il * 16 + c] = f2bf(acc * LOG2E);  // pre-scale for exp2
      }
    }
  }
  __syncthreads();
  float myMean = 0.0f;
  if (t < 16) {
    float dot = 0.0f;
#pragma unroll
    for (int c = 0; c < 16; c++) dot += vf[t * 16 + c] * wsfs[c];
    myMean = (dot + wsfs[16]) * (1.0f / 8192.0f);
  }
  {  // scores via MFMA (log2e-scaled) + exp2; each wave owns a 1024-col slice
    int quad = lane >> 4, n = lane & 15;
    int k8 = quad * 8;
    short8 za = {0, 0, 0, 0, 0, 0, 0, 0};
    short8 a1 = za;
    if (quad < 2) a1 = *(const short8*)&vbf[n * 16 + k8];  // K padded 16->32
    float sacc[4];
#pragma unroll
    for (int q = 0; q < 4; q++) sacc[q] = 0.0f;
    int colb = wave * 1024 + n;
    for (int tp = 0; tp < 64; tp += 2) {
      int col1 = colb + tp * 16;
      int col2 = col1 + 16;
      short8 b1 = za, b2 = za;
      if (quad < 2) {
        b1 = *(const short8*)&w2t[col1 * 16 + k8];
        b2 = *(const short8*)&w2t[col2 * 16 + k8];
      }
      float bb1 = g2b[col1] * LOG2E, bb2 = g2b[col2] * LOG2E;
      float4v c1 = {bb1, bb1, bb1, bb1};
      float4v c2 = {bb2, bb2, bb2, bb2};
      float4v s11 = __builtin_amdgcn_mfma_f32_16x16x32_bf16(a1, b1, c1, 0, 0, 0);
      float4v s12 = __builtin_amdgcn_mfma_f32_16x16x32_bf16(a1, b2, c2, 0, 0, 0);
#pragma unroll
      for (int r = 0; r < 4; r++) sacc[r] += EXP2F(s11[r]) + EXP2F(s12[r]);
    }
#pragma unroll
    for (int q = 0; q < 4; q++) {
      int rl = quad * 4 + q;  // C/D row = quad*4+reg
      pl[rl * 128 + wave * 16 + n] = sacc[q];
    }
  }
  __syncthreads();
  if (t < 128) {
    int r = t >> 3, seg = t & 7;
    int base = r * 128 + seg * 16;
    float ll = 0.0f;
#pragma unroll
    for (int i = 0; i < 16; i++) ll += pl[base + i];
    sl[r * 8 + seg] = ll;
  }
  __syncthreads();
  if (t < 16) {
    float ll = 0.0f;
#pragma unroll
    for (int i = 0; i < 8; i++) ll += sl[t * 8 + i];
    out[256 + rowbase + t] = myMean - __logf(ll);  // ll = sum exp(s)
  }
}

extern "C" void kernel_launch(void* const* d_in, const int* in_sizes, int n_in,
                              void* d_out, int out_size, void* d_ws, size_t ws_size,
                              hipStream_t stream) {
  const float* x     = (const float*)d_in[0];
  const float* x_msg = (const float*)d_in[1];
  const int*   edges = (const int*)d_in[2];
  const int*   action= (const int*)d_in[3];
  const float* c1w   = (const float*)d_in[4];
  const float* c1b   = (const float*)d_in[5];
  const float* c2w   = (const float*)d_in[6];
  const float* c2b   = (const float*)d_in[7];
  const float* fcw   = (const float*)d_in[8];
  const float* fcb   = (const float*)d_in[9];
  const float* muw   = (const float*)d_in[10];
  const float* mub   = (const float*)d_in[11];
  const float* msgw  = (const float*)d_in[12];
  const float* msgb  = (const float*)d_in[13];
  const float* g1w   = (const float*)d_in[14];
  const float* g1b   = (const float*)d_in[15];
  const float* g2w   = (const float*)d_in[16];
  const float* g2b   = (const float*)d_in[17];
  float* out = (float*)d_out;  // reference outputs are fp32

  float* ws     = (float*)d_ws;
  unsigned short* h1024bf = (unsigned short*)ws;            // 262144 bf16 = 131072 f
  unsigned short* fcwbf   = (unsigned short*)(ws + 131072); // 524288 bf16 = 262144 f
  float* hidden = ws + 393216;           // 131072
  float* es2    = ws + 524288;           // 8192
  float* dinv   = ws + 532480;           // 8192
  float* xs2    = ws + 540672;           // 8192
  float* gbuf2  = ws + 548864;           // 131072
  float* wpart  = ws + 679936;           // 8704
  unsigned short* w2t = (unsigned short*)(ws + 688640);     // 131072 bf16 = 65536 f
  int*   cnt    = (int*)(ws + 754176);   // 8192 ints
  int*   csr    = (int*)(ws + 762368);   // 1048576 ints -> ends at float-offset 1810944
  float* wsf    = ws + 1810944;          // 17 (AFTER csr — do not overlap!)

  k_init<<<16, 512, 0, stream>>>(cnt);
  k_pc <<<768, 512, 0, stream>>>(edges, fcw, g2w, g2b, fcwbf, w2t, wpart, cnt, csr,
                                 x, c1w, c1b, c2w, c2b, h1024bf);
  k_fc <<<513, 256, 0, stream>>>(cnt, x_msg, h1024bf, fcwbf, fcb, wpart, hidden, dinv, xs2, wsf);
  k_he <<<512, 512, 0, stream>>>(hidden, muw, mub, msgw, msgb, dinv, action, es2, out);
  k_g1 <<<512, 512, 0, stream>>>(cnt, csr, dinv, xs2, es2, g1w, g1b, gbuf2);
  k_msg<<<512, 512, 0, stream>>>(cnt, csr, dinv, gbuf2, wsf, w2t, g2b, out);
}